// Round 10
// baseline (126.697 us; speedup 1.0000x reference)
//
#include <hip/hip_runtime.h>

typedef unsigned short u16;
typedef unsigned int u32;
typedef __attribute__((ext_vector_type(8))) unsigned short u16x8;
typedef __attribute__((ext_vector_type(8))) short s8v;     // 8 bf16 (MFMA A/B frag)
typedef _Float16 h8 __attribute__((ext_vector_type(8)));   // 8 f16  (MFMA A/B frag)
typedef _Float16 h4 __attribute__((ext_vector_type(4)));
typedef __fp16 fp16x2 __attribute__((ext_vector_type(2)));
typedef __attribute__((ext_vector_type(4))) float f32x4;

__device__ __forceinline__ float b2f(u16 v) {
  union { unsigned int u; float f; } c; c.u = ((unsigned int)v) << 16; return c.f;
}
__device__ __forceinline__ u16 f2b(float f) {
  union { unsigned int u; float f; } c; c.f = f;
  unsigned int u = c.u;
  u += 0x7FFFu + ((u >> 16) & 1u);
  return (u16)(u >> 16);
}
__device__ __forceinline__ u32 pkrtz(float a, float b) {
  union { fp16x2 h; u32 u; } c; c.h = __builtin_amdgcn_cvt_pkrtz(a, b); return c.u;
}
__device__ __forceinline__ u16 f2h_bits(float a) {
  union { _Float16 h; u16 u; } c; c.h = (_Float16)a; return c.u;
}

// ---------------- prep: w -> f16 hi/lo; rel -> bf16 hi/lo + f16 Ve (zero-padded) ---------
// relT: eqhi[256][16B] @0, eqlo @4096, ekhi @8192, eklo @12288, veb[16 d][512 h] @16384 (stride 1024B)
__global__ __launch_bounds__(256) void prep_tables(
    const float* __restrict__ wmat, const float* __restrict__ rel,
    char* __restrict__ whi, char* __restrict__ wlo, char* __restrict__ relT) {
  int tid = threadIdx.x, blk = blockIdx.x;
  if (blk < 32) {
    int i = blk * 1024 + tid;
#pragma unroll
    for (int k = 0; k < 4; k++, i += 256) {
      float v = wmat[i];
      _Float16 h = (_Float16)v;
      ((_Float16*)whi)[i] = h;
      ((_Float16*)wlo)[i] = (_Float16)(v - (float)h);
    }
    return;
  }
  int r = tid;  // 0..255 (255 = zero pad)
  u16x8 qh, ql, kh, kl;
#pragma unroll
  for (int d = 0; d < 8; d++) {
    float vq = (r < 255) ? rel[d * 255 + r] : 0.f;
    u16 hb = f2b(vq); qh[d] = hb; ql[d] = f2b(vq - b2f(hb));
    float vk = (r < 255) ? rel[(8 + d) * 255 + r] : 0.f;
    hb = f2b(vk); kh[d] = hb; kl[d] = f2b(vk - b2f(hb));
  }
  ((u16x8*)(relT + 0))[r] = qh;
  ((u16x8*)(relT + 4096))[r] = ql;
  ((u16x8*)(relT + 8192))[r] = kh;
  ((u16x8*)(relT + 12288))[r] = kl;
#pragma unroll
  for (int d = 0; d < 16; d++) {
    float vv = (r < 255) ? rel[(16 + d) * 255 + r] : 0.f;
    *(_Float16*)(relT + 16384 + d * 1024 + r * 2) = (_Float16)vv;
    *(_Float16*)(relT + 16384 + d * 1024 + (256 + r) * 2) = (_Float16)0.f;  // zero overhang
  }
}

// ---------------- transpose x (B,C,H,W) f32 -> xt2[n][h][c] f16 swizzled ----------------
__global__ __launch_bounds__(256) void transpose_x(
    const float* __restrict__ x, char* __restrict__ xt2) {
  __shared__ _Float16 tile[32][33];
  int z = blockIdx.z, b = z >> 7, h = z & 127;
  const float* s = x + (size_t)b * 2097152 + h * 128;
  int tx = threadIdx.x, ty = threadIdx.y;
  int c0 = blockIdx.y * 32, w0 = blockIdx.x * 32;
#pragma unroll
  for (int k = 0; k < 4; k++)
    tile[ty + k * 8][tx] = (_Float16)s[(size_t)(c0 + ty + k * 8) * 16384 + w0 + tx];
  __syncthreads();
#pragma unroll
  for (int k = 0; k < 4; k++) {
    int w = w0 + ty + k * 8;
    int n = b * 128 + w;
    int c = c0 + tx;
    *(_Float16*)(xt2 + (size_t)n * 32768 + h * 256 + ((((c >> 3) ^ (h & 7))) << 4) + (c & 7) * 2) =
        tile[tx][ty + k * 8];
  }
}

// ---------------- kqv MFMA GEMM + BN + preformat emission (unchanged) ----------------
#define KQ_XS 0
#define KQ_FMT 16384
#define KQ_INV 33792
#define KQ_BIA 34816
#define LDS_K 35840
__global__ __launch_bounds__(256, 2) void kqv_mfma(
    const char* __restrict__ xt2, const char* __restrict__ whi, const char* __restrict__ wlo,
    const float* __restrict__ gam, const float* __restrict__ bet,
    const float* __restrict__ mea, const float* __restrict__ var,
    char* __restrict__ qkT, char* __restrict__ vT) {
  __shared__ __attribute__((aligned(16))) char sm[LDS_K];
  int tid = threadIdx.x;
  int h0 = 64 * blockIdx.x, n = blockIdx.y;
  int lane = tid & 63, wv = tid >> 6, g = lane >> 4, l15 = lane & 15;
  const char* src = xt2 + (size_t)n * 32768 + h0 * 256;
  for (int i = tid; i < 1024; i += 256)
    ((f32x4*)(sm + KQ_XS))[i] = ((const f32x4*)src)[i];
  {
    float gv = gam[tid], bb = bet[tid], mm = mea[tid], vv = var[tid];
    float inv = gv * rsqrtf(vv + 1e-5f);
    ((float*)(sm + KQ_INV))[tid] = inv;
    ((float*)(sm + KQ_BIA))[tid] = bb - mm * inv;
  }
  __syncthreads();
  f32x4 acc[4][4];
#pragma unroll
  for (int a = 0; a < 4; a++)
#pragma unroll
    for (int b = 0; b < 4; b++) acc[a][b] = (f32x4){0.f, 0.f, 0.f, 0.f};
  const char* wsel = (g & 1) ? wlo : whi;
  int cofs = (g >> 1) * 8;
#pragma unroll
  for (int kk = 0; kk < 8; kk++) {
    h8 af[4], bf[4];
#pragma unroll
    for (int tt = 0; tt < 4; tt++)
      af[tt] = *(const h8*)(wsel + (64 * wv + 16 * tt + l15) * 256 + (16 * kk + cofs) * 2);
#pragma unroll
    for (int ht = 0; ht < 4; ht++)
      bf[ht] = *(const h8*)(sm + KQ_XS + (16 * ht + l15) * 256 +
                            (((2 * kk + (g >> 1)) ^ (l15 & 7)) << 4));
#pragma unroll
    for (int tt = 0; tt < 4; tt++)
#pragma unroll
      for (int ht = 0; ht < 4; ht++)
        acc[tt][ht] = __builtin_amdgcn_mfma_f32_16x16x32_f16(af[tt], bf[ht], acc[tt][ht], 0, 0, 0);
  }
  for (int r = 0; r < 4; r++) {
    if (wv == r) {
#pragma unroll
      for (int tt = 0; tt < 4; tt++)
#pragma unroll
        for (int ht = 0; ht < 4; ht++) {
          int ob = 16 * tt + 4 * g;
#pragma unroll
          for (int i = 0; i < 4; i++) {
            int o = 64 * r + ob + i;
            float inv = ((float*)(sm + KQ_INV))[o];
            float bia = ((float*)(sm + KQ_BIA))[o];
            ((float*)(sm + KQ_FMT))[(ob + i) * 68 + 16 * ht + l15] = acc[tt][ht][i] * inv + bia;
          }
        }
    }
    __syncthreads();
    {  // QK planes: Khi@0, Klo@2048, Qhi@4096, Qlo@6144 per (n,head)
      int xl = tid & 63, hsel = (tid >> 6) & 1, kq = tid >> 7;
      int headi = 2 * r + hsel;
      int obl = hsel * 32 + kq * 8;
      u16x8 hi8, lo8;
#pragma unroll
      for (int d = 0; d < 8; d++) {
        float v = ((float*)(sm + KQ_FMT))[(obl + d) * 68 + xl];
        u16 hb = f2b(v);
        hi8[d] = hb;
        lo8[d] = f2b(v - b2f(hb));
      }
      char* dsth = qkT + (size_t)(n * 8 + headi) * 8192 + (kq * 2) * 2048 + (h0 + xl) * 16;
      *(u16x8*)dsth = hi8;
      *(u16x8*)(dsth + 2048) = lo8;
    }
    {  // V: [16 d][128 x] f16
      int hsel = tid >> 7, d = (tid >> 3) & 15, xo = tid & 7;
      int headi = 2 * r + hsel;
      h8 vv;
#pragma unroll
      for (int j = 0; j < 8; j++)
        vv[j] = (_Float16)((float*)(sm + KQ_FMT))[(hsel * 32 + 16 + d) * 68 + xo * 8 + j];
      *(h8*)(vT + (size_t)(n * 8 + headi) * 4096 + d * 256 + (h0 + xo * 8) * 2) = vv;
    }
    __syncthreads();
  }
}

// ---------------- attention v7: spill fix — no eqf preload (per-use loads) ----------------
// per-wave scratch 9472B, phase-aliased:
//   T1 (R1): f32 [16 x][148 dw] stride 592            (9472B)
//   R2: 2 f32 bufs [16 y][50 dw] stride 200           (6400B)
//   Pun: f16 [32 j][140] stride 280                   (8960B)
//   Psk: f16 [16 j][172] stride 344                   (5504B)
#define SW_BYTES 9472
#define T1_STRIDE 592
#define LDS_A 37888
__global__ __launch_bounds__(256, 4) void attn_mfma7(
    const char* __restrict__ qkT, const char* __restrict__ vT, const char* __restrict__ relT,
    const float* __restrict__ lg, const float* __restrict__ lb,
    const float* __restrict__ lm, const float* __restrict__ lv,
    _Float16* __restrict__ otmp) {
  __shared__ __attribute__((aligned(16))) char sm[LDS_A];
  const int tid = threadIdx.x;
  const int head = blockIdx.x, n = blockIdx.y;
  const int lane = tid & 63, wv = tid >> 6;
  const int g = lane >> 4, l15 = lane & 15;
  char* sw = sm + wv * SW_BYTES;
  const char* qkb = qkT + (size_t)(n * 8 + head) * 8192;
  const char* vb = vT + (size_t)(n * 8 + head) * 4096;
  // A-side hi/lo by (g&1) = (hi,lo,hi,lo); B-side by (g>>1) = (hi,hi,lo,lo)
  const char* kAp = qkb + ((g & 1) ? 2048 : 0);
  const char* kBp = qkb + ((g >> 1) ? 2048 : 0);
  const char* qBp = qkb + 4096 + ((g >> 1) ? 2048 : 0);
  const char* eqA = relT + ((g & 1) ? 4096 : 0);
  const char* ekA = relT + 8192 + ((g & 1) ? 4096 : 0);
  const char* veB = relT + 16384;  // [16 d][512 h], stride 1024B

  const float LOG2E = 1.44269504088896340736f;
  float a0 = LOG2E * lg[head] * rsqrtf(lv[head] + 1e-5f);
  float a1 = LOG2E * lg[8 + head] * rsqrtf(lv[8 + head] + 1e-5f);
  float a2 = LOG2E * lg[16 + head] * rsqrtf(lv[16 + head] + 1e-5f);
  float bsum = (LOG2E * lb[head] - lm[head] * a0) + (LOG2E * lb[8 + head] - lm[8 + head] * a1) +
               (LOG2E * lb[16 + head] - lm[16 + head] * a2);

  const f32x4 zero4 = {0.f, 0.f, 0.f, 0.f};
  const int X0a = 32 * wv, X0b = X0a + 16;

  // ---- S0: lane holds S[x = X0+l15][y = 16yt+4g+i] (A=k, B=q); logits pre-scaled by log2e ----
  s8v qfA = *(const s8v*)(qBp + (X0a + l15) * 16);
  s8v qfB = *(const s8v*)(qBp + (X0b + l15) * 16);
  f32x4 s0[8], s1[8];
#pragma unroll
  for (int yt = 0; yt < 8; yt++) {
    s8v ka = *(const s8v*)(kAp + (yt * 16 + l15) * 16);
    f32x4 d0 = __builtin_amdgcn_mfma_f32_16x16x32_bf16(ka, qfA, zero4, 0, 0, 0);
    f32x4 d1 = __builtin_amdgcn_mfma_f32_16x16x32_bf16(ka, qfB, zero4, 0, 0, 0);
#pragma unroll
    for (int i = 0; i < 4; i++) {
      s0[yt][i] = a0 * d0[i] + bsum;
      s1[yt][i] = a0 * d1[i] + bsum;
    }
  }

  // ---- R1: Rq[r][x]; f32 scratch, per-use Eq loads (register diet vs eqf[10]) ----
  {
    int rbu = 96 - X0a;  // tile-a uses rows rbu+16(t+1), tile-b rows rbu+16t
#pragma unroll
    for (int t = 0; t < 9; t++) {
      s8v eb = *(const s8v*)(eqA + (rbu + 16 * (t + 1) + l15) * 16);
      f32x4 d = __builtin_amdgcn_mfma_f32_16x16x32_bf16(eb, qfA, zero4, 0, 0, 0);
      *(f32x4*)(sw + l15 * T1_STRIDE + (16 * t + 4 * g) * 4) = d;
    }
    {
      const float* r1p = (const float*)(sw + l15 * T1_STRIDE) + (4 * g + 15 - l15);
#pragma unroll
      for (int yt = 0; yt < 8; yt++)
#pragma unroll
        for (int i = 0; i < 4; i++) s0[yt][i] += a1 * r1p[16 * yt + i];
    }
#pragma unroll
    for (int t = 0; t < 9; t++) {
      s8v eb = *(const s8v*)(eqA + (rbu + 16 * t + l15) * 16);
      f32x4 d = __builtin_amdgcn_mfma_f32_16x16x32_bf16(eb, qfB, zero4, 0, 0, 0);
      *(f32x4*)(sw + l15 * T1_STRIDE + (16 * t + 4 * g) * 4) = d;
    }
    {
      const float* r1p = (const float*)(sw + l15 * T1_STRIDE) + (4 * g + 15 - l15);
#pragma unroll
      for (int yt = 0; yt < 8; yt++)
#pragma unroll
        for (int i = 0; i < 4; i++) s1[yt][i] += a1 * r1p[16 * yt + i];
    }
  }

  // ---- R2: produce pair (bufA,bufB) then merge pair ----
  {
    char* bufA = sw;
    char* bufB = sw + 3200;
#pragma unroll
    for (int grp = 0; grp < 4; grp++) {
      int ytA = 2 * grp, ytB = 2 * grp + 1;
      {
        int rb2 = X0a - 16 * ytA + 112;
        s8v kf = *(const s8v*)(kBp + (16 * ytA + l15) * 16);
#pragma unroll
        for (int t = 0; t < 3; t++) {
          s8v ef = *(const s8v*)(ekA + (rb2 + 16 * t + l15) * 16);
          f32x4 d = __builtin_amdgcn_mfma_f32_16x16x32_bf16(ef, kf, zero4, 0, 0, 0);
          *(f32x4*)(bufA + l15 * 200 + (16 * t + 4 * g) * 4) = d;
        }
      }
      {
        int rb2 = X0a - 16 * ytB + 112;
        s8v kf = *(const s8v*)(kBp + (16 * ytB + l15) * 16);
#pragma unroll
        for (int t = 0; t < 3; t++) {
          s8v ef = *(const s8v*)(ekA + (rb2 + 16 * t + l15) * 16);
          f32x4 d = __builtin_amdgcn_mfma_f32_16x16x32_bf16(ef, kf, zero4, 0, 0, 0);
          *(f32x4*)(bufB + l15 * 200 + (16 * t + 4 * g) * 4) = d;
        }
      }
#pragma unroll
      for (int i = 0; i < 4; i++) {
        const float* bpA = (const float*)(bufA + (4 * g + i) * 200) + (l15 + 15 - 4 * g - i);
        s0[ytA][i] += a2 * bpA[0];
        s1[ytA][i] += a2 * bpA[16];
        const float* bpB = (const float*)(bufB + (4 * g + i) * 200) + (l15 + 15 - 4 * g - i);
        s0[ytB][i] += a2 * bpB[0];
        s1[ytB][i] += a2 * bpB[16];
      }
    }
  }

  // ---- softmax in base-2 (logits pre-scaled); row x per lane; shfl_xor 16,32 reduce ----
  float rl0, rl1;
  {
    float m0 = -1e30f, m1 = -1e30f;
#pragma unroll
    for (int yt = 0; yt < 8; yt++) {
      m0 = fmaxf(fmaxf(m0, s0[yt][0]), s0[yt][1]);
      m0 = fmaxf(fmaxf(m0, s0[yt][2]), s0[yt][3]);
      m1 = fmaxf(fmaxf(m1, s1[yt][0]), s1[yt][1]);
      m1 = fmaxf(fmaxf(m1, s1[yt][2]), s1[yt][3]);
    }
    m0 = fmaxf(m0, __shfl_xor(m0, 16)); m0 = fmaxf(m0, __shfl_xor(m0, 32));
    m1 = fmaxf(m1, __shfl_xor(m1, 16)); m1 = fmaxf(m1, __shfl_xor(m1, 32));
    float l0 = 0.f, l1 = 0.f;
#pragma unroll
    for (int yt = 0; yt < 8; yt++)
#pragma unroll
      for (int i = 0; i < 4; i++) {
        float p0 = exp2f(s0[yt][i] - m0); s0[yt][i] = p0; l0 += p0;
        float p1 = exp2f(s1[yt][i] - m1); s1[yt][i] = p1; l1 += p1;
      }
    l0 += __shfl_xor(l0, 16); l0 += __shfl_xor(l0, 32);
    l1 += __shfl_xor(l1, 16); l1 += __shfl_xor(l1, 32);
    rl0 = 1.f / l0; rl1 = 1.f / l1;
  }

  // ---- Pun stores (cvt_pkrtz): [32 j][140 h] stride 280 ----
#pragma unroll
  for (int yt = 0; yt < 8; yt++) {
    char* pa = sw + l15 * 280 + (16 * yt + 4 * g) * 2;
    *(u32*)pa = pkrtz(s0[yt][0], s0[yt][1]);
    *(u32*)(pa + 4) = pkrtz(s0[yt][2], s0[yt][3]);
    char* pb = sw + (16 + l15) * 280 + (16 * yt + 4 * g) * 2;
    *(u32*)pb = pkrtz(s1[yt][0], s1[yt][1]);
    *(u32*)(pb + 4) = pkrtz(s1[yt][2], s1[yt][3]);
  }
  // ---- PV: A=V (global), B=Pun rows ----
  f32x4 acc0 = zero4, acc1 = zero4;
#pragma unroll
  for (int ky = 0; ky < 4; ky++) {
    h8 vf = *(const h8*)(vb + l15 * 256 + (32 * ky + 8 * g) * 2);
    h8 p0 = *(const h8*)(sw + l15 * 280 + (32 * ky + 8 * g) * 2);
    h8 p1 = *(const h8*)(sw + (16 + l15) * 280 + (32 * ky + 8 * g) * 2);
    acc0 = __builtin_amdgcn_mfma_f32_16x16x32_f16(vf, p0, acc0, 0, 0, 0);
    acc1 = __builtin_amdgcn_mfma_f32_16x16x32_f16(vf, p1, acc1, 0, 0, 0);
  }

  // ---- PVenc: Psk [16 j][172] stride 344, zero once, per-tile store+5 MFMA ----
  for (int i = lane; i < 344; i += 64) *(f32x4*)(sw + i * 16) = zero4;  // 5504B zero
  {  // tile a
#pragma unroll
    for (int yt = 0; yt < 8; yt++)
#pragma unroll
      for (int i = 0; i < 4; i++) {
        int col = 16 * yt + 4 * g + i - l15 + 15;
        *(u16*)(sw + l15 * 344 + col * 2) = f2h_bits(s0[yt][i]);
      }
    int rb_a = 112 - X0a;
#pragma unroll
    for (int t = 0; t < 5; t++) {
      h8 vef = *(const h8*)(veB + l15 * 1024 + (rb_a + 32 * t + 8 * g) * 2);
      h8 skf = *(const h8*)(sw + l15 * 344 + (32 * t + 8 * g) * 2);
      acc0 = __builtin_amdgcn_mfma_f32_16x16x32_f16(vef, skf, acc0, 0, 0, 0);
    }
  }
  {  // tile b (full data-region overwrite; pads stay zero)
#pragma unroll
    for (int yt = 0; yt < 8; yt++)
#pragma unroll
      for (int i = 0; i < 4; i++) {
        int col = 16 * yt + 4 * g + i - l15 + 15;
        *(u16*)(sw + l15 * 344 + col * 2) = f2h_bits(s1[yt][i]);
      }
    int rb_b = 96 - X0a;
#pragma unroll
    for (int t = 0; t < 5; t++) {
      h8 vef = *(const h8*)(veB + l15 * 1024 + (rb_b + 32 * t + 8 * g) * 2);
      h8 skf = *(const h8*)(sw + l15 * 344 + (32 * t + 8 * g) * 2);
      acc1 = __builtin_amdgcn_mfma_f32_16x16x32_f16(vef, skf, acc1, 0, 0, 0);
    }
  }

  // ---- normalize + write otmp[n][c][x] f16 ----
  size_t obase = (size_t)(n * 8 + head) * 2048;
#pragma unroll
  for (int i = 0; i < 4; i++) {
    int d = 4 * g + i;
    otmp[obase + d * 128 + X0a + l15] = (_Float16)(acc0[i] * rl0);
    otmp[obase + d * 128 + X0b + l15] = (_Float16)(acc1[i] * rl1);
  }
}

// ---------------- otmp f16 -> out f32 transpose ----------------
__global__ __launch_bounds__(256) void transpose_h2f(
    const u16* __restrict__ src, float* __restrict__ dst,
    int sb, int sc, int sstr, int db, int dc, int dstr) {
  __shared__ u16 tile[32][33];
  int z = blockIdx.z, b = z >> 7, c = z & 127;
  const u16* s = src + (size_t)b * sb + c * sc;
  float* d = dst + (size_t)b * db + c * dc;
  int tx = threadIdx.x, ty = threadIdx.y;
  int r0 = blockIdx.y * 32, c0 = blockIdx.x * 32;
#pragma unroll
  for (int k = 0; k < 4; k++)
    tile[ty + k * 8][tx] = s[(size_t)(r0 + ty + k * 8) * sstr + c0 + tx];
  __syncthreads();
#pragma unroll
  for (int k = 0; k < 4; k++) {
    u16 hv = tile[tx][ty + k * 8];
    d[(size_t)(c0 + ty + k * 8) * dstr + r0 + tx] = (float)(*(const _Float16*)&hv);
  }
}

extern "C" void kernel_launch(void* const* d_in, const int* in_sizes, int n_in,
                              void* d_out, int out_size, void* d_ws, size_t ws_size,
                              hipStream_t stream) {
  const float* x     = (const float*)d_in[0];
  const float* kqv_w = (const float*)d_in[1];
  const float* kqv_g = (const float*)d_in[2];
  const float* kqv_b = (const float*)d_in[3];
  const float* kqv_m = (const float*)d_in[4];
  const float* kqv_v = (const float*)d_in[5];
  const float* lg    = (const float*)d_in[6];
  const float* lb    = (const float*)d_in[7];
  const float* lm    = (const float*)d_in[8];
  const float* lv    = (const float*)d_in[9];
  const float* rel   = (const float*)d_in[10];
  float* out = (float*)d_out;

  char* ws = (char*)d_ws;
  char* xt2  = ws;                              //  8 MiB f16 swizzled [n][h][c]
  char* qkT  = ws + 8388608;                    // 16 MiB bf16 hi/lo planes
  char* vT   = ws + 25165824;                   //  8 MiB f16 [n,h][d][x]
  _Float16* otmp = (_Float16*)(ws + 33554432);  //  8 MiB f16
  char* whi  = ws + 41943040;                   // 64 KiB
  char* wlo  = ws + 42008576;                   // 64 KiB
  char* relT = ws + 42074112;                   // 32 KiB

  prep_tables<<<33, 256, 0, stream>>>(kqv_w, rel, whi, wlo, relT);
  transpose_x<<<dim3(4, 4, 256), dim3(32, 8), 0, stream>>>(x, xt2);
  kqv_mfma<<<dim3(2, 256), 256, 0, stream>>>(xt2, whi, wlo, kqv_g, kqv_b, kqv_m, kqv_v, qkT, vT);
  attn_mfma7<<<dim3(8, 256), 256, 0, stream>>>(qkT, vT, relT, lg, lb, lm, lv, otmp);
  transpose_h2f<<<dim3(4, 4, 256), dim3(32, 8), 0, stream>>>(
      (const u16*)otmp, out, 2097152, 128, 16384, 2097152, 16384, 128);
}

// Round 11
// 112.344 us; speedup vs baseline: 1.1278x; 1.1278x over previous
//
#include <hip/hip_runtime.h>

typedef unsigned short u16;
typedef unsigned int u32;
typedef __attribute__((ext_vector_type(8))) unsigned short u16x8;
typedef __attribute__((ext_vector_type(8))) short s8v;     // 8 bf16 (MFMA A/B frag)
typedef _Float16 h8 __attribute__((ext_vector_type(8)));   // 8 f16  (MFMA A/B frag)
typedef _Float16 h4 __attribute__((ext_vector_type(4)));
typedef __fp16 fp16x2 __attribute__((ext_vector_type(2)));
typedef __attribute__((ext_vector_type(4))) float f32x4;

__device__ __forceinline__ float b2f(u16 v) {
  union { unsigned int u; float f; } c; c.u = ((unsigned int)v) << 16; return c.f;
}
__device__ __forceinline__ u16 f2b(float f) {
  union { unsigned int u; float f; } c; c.f = f;
  unsigned int u = c.u;
  u += 0x7FFFu + ((u >> 16) & 1u);
  return (u16)(u >> 16);
}
__device__ __forceinline__ u32 pkrtz(float a, float b) {
  union { fp16x2 h; u32 u; } c; c.h = __builtin_amdgcn_cvt_pkrtz(a, b); return c.u;
}
__device__ __forceinline__ u16 f2h_bits(float a) {
  union { _Float16 h; u16 u; } c; c.h = (_Float16)a; return c.u;
}

// ---------------- prep: w -> f16 hi/lo; rel -> bf16 hi/lo + f16 Ve (zero-padded) ---------
// relT: eqhi[256][16B] @0, eqlo @4096, ekhi @8192, eklo @12288, veb[16 d][512 h] @16384 (stride 1024B)
__global__ __launch_bounds__(256) void prep_tables(
    const float* __restrict__ wmat, const float* __restrict__ rel,
    char* __restrict__ whi, char* __restrict__ wlo, char* __restrict__ relT) {
  int tid = threadIdx.x, blk = blockIdx.x;
  if (blk < 32) {
    int i = blk * 1024 + tid;
#pragma unroll
    for (int k = 0; k < 4; k++, i += 256) {
      float v = wmat[i];
      _Float16 h = (_Float16)v;
      ((_Float16*)whi)[i] = h;
      ((_Float16*)wlo)[i] = (_Float16)(v - (float)h);
    }
    return;
  }
  int r = tid;  // 0..255 (255 = zero pad)
  u16x8 qh, ql, kh, kl;
#pragma unroll
  for (int d = 0; d < 8; d++) {
    float vq = (r < 255) ? rel[d * 255 + r] : 0.f;
    u16 hb = f2b(vq); qh[d] = hb; ql[d] = f2b(vq - b2f(hb));
    float vk = (r < 255) ? rel[(8 + d) * 255 + r] : 0.f;
    hb = f2b(vk); kh[d] = hb; kl[d] = f2b(vk - b2f(hb));
  }
  ((u16x8*)(relT + 0))[r] = qh;
  ((u16x8*)(relT + 4096))[r] = ql;
  ((u16x8*)(relT + 8192))[r] = kh;
  ((u16x8*)(relT + 12288))[r] = kl;
#pragma unroll
  for (int d = 0; d < 16; d++) {
    float vv = (r < 255) ? rel[(16 + d) * 255 + r] : 0.f;
    *(_Float16*)(relT + 16384 + d * 1024 + r * 2) = (_Float16)vv;
    *(_Float16*)(relT + 16384 + d * 1024 + (256 + r) * 2) = (_Float16)0.f;  // zero overhang
  }
}

// ---------------- transpose x (B,C,H,W) f32 -> xt2[n][h][c] f16 swizzled ----------------
__global__ __launch_bounds__(256) void transpose_x(
    const float* __restrict__ x, char* __restrict__ xt2) {
  __shared__ _Float16 tile[32][33];
  int z = blockIdx.z, b = z >> 7, h = z & 127;
  const float* s = x + (size_t)b * 2097152 + h * 128;
  int tx = threadIdx.x, ty = threadIdx.y;
  int c0 = blockIdx.y * 32, w0 = blockIdx.x * 32;
#pragma unroll
  for (int k = 0; k < 4; k++)
    tile[ty + k * 8][tx] = (_Float16)s[(size_t)(c0 + ty + k * 8) * 16384 + w0 + tx];
  __syncthreads();
#pragma unroll
  for (int k = 0; k < 4; k++) {
    int w = w0 + ty + k * 8;
    int n = b * 128 + w;
    int c = c0 + tx;
    *(_Float16*)(xt2 + (size_t)n * 32768 + h * 256 + ((((c >> 3) ^ (h & 7))) << 4) + (c & 7) * 2) =
        tile[tx][ty + k * 8];
  }
}

// ---------------- kqv MFMA GEMM + BN + preformat emission (unchanged) ----------------
#define KQ_XS 0
#define KQ_FMT 16384
#define KQ_INV 33792
#define KQ_BIA 34816
#define LDS_K 35840
__global__ __launch_bounds__(256, 2) void kqv_mfma(
    const char* __restrict__ xt2, const char* __restrict__ whi, const char* __restrict__ wlo,
    const float* __restrict__ gam, const float* __restrict__ bet,
    const float* __restrict__ mea, const float* __restrict__ var,
    char* __restrict__ qkT, char* __restrict__ vT) {
  __shared__ __attribute__((aligned(16))) char sm[LDS_K];
  int tid = threadIdx.x;
  int h0 = 64 * blockIdx.x, n = blockIdx.y;
  int lane = tid & 63, wv = tid >> 6, g = lane >> 4, l15 = lane & 15;
  const char* src = xt2 + (size_t)n * 32768 + h0 * 256;
  for (int i = tid; i < 1024; i += 256)
    ((f32x4*)(sm + KQ_XS))[i] = ((const f32x4*)src)[i];
  {
    float gv = gam[tid], bb = bet[tid], mm = mea[tid], vv = var[tid];
    float inv = gv * rsqrtf(vv + 1e-5f);
    ((float*)(sm + KQ_INV))[tid] = inv;
    ((float*)(sm + KQ_BIA))[tid] = bb - mm * inv;
  }
  __syncthreads();
  f32x4 acc[4][4];
#pragma unroll
  for (int a = 0; a < 4; a++)
#pragma unroll
    for (int b = 0; b < 4; b++) acc[a][b] = (f32x4){0.f, 0.f, 0.f, 0.f};
  const char* wsel = (g & 1) ? wlo : whi;
  int cofs = (g >> 1) * 8;
#pragma unroll
  for (int kk = 0; kk < 8; kk++) {
    h8 af[4], bf[4];
#pragma unroll
    for (int tt = 0; tt < 4; tt++)
      af[tt] = *(const h8*)(wsel + (64 * wv + 16 * tt + l15) * 256 + (16 * kk + cofs) * 2);
#pragma unroll
    for (int ht = 0; ht < 4; ht++)
      bf[ht] = *(const h8*)(sm + KQ_XS + (16 * ht + l15) * 256 +
                            (((2 * kk + (g >> 1)) ^ (l15 & 7)) << 4));
#pragma unroll
    for (int tt = 0; tt < 4; tt++)
#pragma unroll
      for (int ht = 0; ht < 4; ht++)
        acc[tt][ht] = __builtin_amdgcn_mfma_f32_16x16x32_f16(af[tt], bf[ht], acc[tt][ht], 0, 0, 0);
  }
  for (int r = 0; r < 4; r++) {
    if (wv == r) {
#pragma unroll
      for (int tt = 0; tt < 4; tt++)
#pragma unroll
        for (int ht = 0; ht < 4; ht++) {
          int ob = 16 * tt + 4 * g;
#pragma unroll
          for (int i = 0; i < 4; i++) {
            int o = 64 * r + ob + i;
            float inv = ((float*)(sm + KQ_INV))[o];
            float bia = ((float*)(sm + KQ_BIA))[o];
            ((float*)(sm + KQ_FMT))[(ob + i) * 68 + 16 * ht + l15] = acc[tt][ht][i] * inv + bia;
          }
        }
    }
    __syncthreads();
    {  // QK planes: Khi@0, Klo@2048, Qhi@4096, Qlo@6144 per (n,head)
      int xl = tid & 63, hsel = (tid >> 6) & 1, kq = tid >> 7;
      int headi = 2 * r + hsel;
      int obl = hsel * 32 + kq * 8;
      u16x8 hi8, lo8;
#pragma unroll
      for (int d = 0; d < 8; d++) {
        float v = ((float*)(sm + KQ_FMT))[(obl + d) * 68 + xl];
        u16 hb = f2b(v);
        hi8[d] = hb;
        lo8[d] = f2b(v - b2f(hb));
      }
      char* dsth = qkT + (size_t)(n * 8 + headi) * 8192 + (kq * 2) * 2048 + (h0 + xl) * 16;
      *(u16x8*)dsth = hi8;
      *(u16x8*)(dsth + 2048) = lo8;
    }
    {  // V: [16 d][128 x] f16
      int hsel = tid >> 7, d = (tid >> 3) & 15, xo = tid & 7;
      int headi = 2 * r + hsel;
      h8 vv;
#pragma unroll
      for (int j = 0; j < 8; j++)
        vv[j] = (_Float16)((float*)(sm + KQ_FMT))[(hsel * 32 + 16 + d) * 68 + xo * 8 + j];
      *(h8*)(vT + (size_t)(n * 8 + headi) * 4096 + d * 256 + (h0 + xo * 8) * 2) = vv;
    }
    __syncthreads();
  }
}

// ---------------- attention v8: launch_bounds (256,2) — avoid the 64/64 arch/acc split spill ----
// per-wave scratch 9472B, phase-aliased:
//   T1 (R1): f32 [16 x][148 dw] stride 592            (9472B)
//   R2: 2 f32 bufs [16 y][50 dw] stride 200           (6400B)
//   Pun: f16 [32 j][140] stride 280                   (8960B)
//   Psk: f16 [16 j][172] stride 344                   (5504B)
#define SW_BYTES 9472
#define T1_STRIDE 592
#define LDS_A 37888
__global__ __launch_bounds__(256, 2) void attn_mfma8(
    const char* __restrict__ qkT, const char* __restrict__ vT, const char* __restrict__ relT,
    const float* __restrict__ lg, const float* __restrict__ lb,
    const float* __restrict__ lm, const float* __restrict__ lv,
    _Float16* __restrict__ otmp) {
  __shared__ __attribute__((aligned(16))) char sm[LDS_A];
  const int tid = threadIdx.x;
  const int head = blockIdx.x, n = blockIdx.y;
  const int lane = tid & 63, wv = tid >> 6;
  const int g = lane >> 4, l15 = lane & 15;
  char* sw = sm + wv * SW_BYTES;
  const char* qkb = qkT + (size_t)(n * 8 + head) * 8192;
  const char* vb = vT + (size_t)(n * 8 + head) * 4096;
  // A-side hi/lo by (g&1) = (hi,lo,hi,lo); B-side by (g>>1) = (hi,hi,lo,lo)
  const char* kAp = qkb + ((g & 1) ? 2048 : 0);
  const char* kBp = qkb + ((g >> 1) ? 2048 : 0);
  const char* qBp = qkb + 4096 + ((g >> 1) ? 2048 : 0);
  const char* eqA = relT + ((g & 1) ? 4096 : 0);
  const char* ekA = relT + 8192 + ((g & 1) ? 4096 : 0);
  const char* veB = relT + 16384;  // [16 d][512 h], stride 1024B

  const float LOG2E = 1.44269504088896340736f;
  float a0 = LOG2E * lg[head] * rsqrtf(lv[head] + 1e-5f);
  float a1 = LOG2E * lg[8 + head] * rsqrtf(lv[8 + head] + 1e-5f);
  float a2 = LOG2E * lg[16 + head] * rsqrtf(lv[16 + head] + 1e-5f);
  float bsum = (LOG2E * lb[head] - lm[head] * a0) + (LOG2E * lb[8 + head] - lm[8 + head] * a1) +
               (LOG2E * lb[16 + head] - lm[16 + head] * a2);

  const f32x4 zero4 = {0.f, 0.f, 0.f, 0.f};
  const int X0a = 32 * wv, X0b = X0a + 16;

  // ---- S0: lane holds S[x = X0+l15][y = 16yt+4g+i] (A=k, B=q); logits pre-scaled by log2e ----
  s8v qfA = *(const s8v*)(qBp + (X0a + l15) * 16);
  s8v qfB = *(const s8v*)(qBp + (X0b + l15) * 16);
  f32x4 s0[8], s1[8];
#pragma unroll
  for (int yt = 0; yt < 8; yt++) {
    s8v ka = *(const s8v*)(kAp + (yt * 16 + l15) * 16);
    f32x4 d0 = __builtin_amdgcn_mfma_f32_16x16x32_bf16(ka, qfA, zero4, 0, 0, 0);
    f32x4 d1 = __builtin_amdgcn_mfma_f32_16x16x32_bf16(ka, qfB, zero4, 0, 0, 0);
#pragma unroll
    for (int i = 0; i < 4; i++) {
      s0[yt][i] = a0 * d0[i] + bsum;
      s1[yt][i] = a0 * d1[i] + bsum;
    }
  }

  // ---- R1: Rq[r][x]; f32 scratch, per-use Eq loads ----
  {
    int rbu = 96 - X0a;  // tile-a uses rows rbu+16(t+1), tile-b rows rbu+16t
#pragma unroll
    for (int t = 0; t < 9; t++) {
      s8v eb = *(const s8v*)(eqA + (rbu + 16 * (t + 1) + l15) * 16);
      f32x4 d = __builtin_amdgcn_mfma_f32_16x16x32_bf16(eb, qfA, zero4, 0, 0, 0);
      *(f32x4*)(sw + l15 * T1_STRIDE + (16 * t + 4 * g) * 4) = d;
    }
    {
      const float* r1p = (const float*)(sw + l15 * T1_STRIDE) + (4 * g + 15 - l15);
#pragma unroll
      for (int yt = 0; yt < 8; yt++)
#pragma unroll
        for (int i = 0; i < 4; i++) s0[yt][i] += a1 * r1p[16 * yt + i];
    }
#pragma unroll
    for (int t = 0; t < 9; t++) {
      s8v eb = *(const s8v*)(eqA + (rbu + 16 * t + l15) * 16);
      f32x4 d = __builtin_amdgcn_mfma_f32_16x16x32_bf16(eb, qfB, zero4, 0, 0, 0);
      *(f32x4*)(sw + l15 * T1_STRIDE + (16 * t + 4 * g) * 4) = d;
    }
    {
      const float* r1p = (const float*)(sw + l15 * T1_STRIDE) + (4 * g + 15 - l15);
#pragma unroll
      for (int yt = 0; yt < 8; yt++)
#pragma unroll
        for (int i = 0; i < 4; i++) s1[yt][i] += a1 * r1p[16 * yt + i];
    }
  }

  // ---- R2: produce pair (bufA,bufB) then merge pair ----
  {
    char* bufA = sw;
    char* bufB = sw + 3200;
#pragma unroll
    for (int grp = 0; grp < 4; grp++) {
      int ytA = 2 * grp, ytB = 2 * grp + 1;
      {
        int rb2 = X0a - 16 * ytA + 112;
        s8v kf = *(const s8v*)(kBp + (16 * ytA + l15) * 16);
#pragma unroll
        for (int t = 0; t < 3; t++) {
          s8v ef = *(const s8v*)(ekA + (rb2 + 16 * t + l15) * 16);
          f32x4 d = __builtin_amdgcn_mfma_f32_16x16x32_bf16(ef, kf, zero4, 0, 0, 0);
          *(f32x4*)(bufA + l15 * 200 + (16 * t + 4 * g) * 4) = d;
        }
      }
      {
        int rb2 = X0a - 16 * ytB + 112;
        s8v kf = *(const s8v*)(kBp + (16 * ytB + l15) * 16);
#pragma unroll
        for (int t = 0; t < 3; t++) {
          s8v ef = *(const s8v*)(ekA + (rb2 + 16 * t + l15) * 16);
          f32x4 d = __builtin_amdgcn_mfma_f32_16x16x32_bf16(ef, kf, zero4, 0, 0, 0);
          *(f32x4*)(bufB + l15 * 200 + (16 * t + 4 * g) * 4) = d;
        }
      }
#pragma unroll
      for (int i = 0; i < 4; i++) {
        const float* bpA = (const float*)(bufA + (4 * g + i) * 200) + (l15 + 15 - 4 * g - i);
        s0[ytA][i] += a2 * bpA[0];
        s1[ytA][i] += a2 * bpA[16];
        const float* bpB = (const float*)(bufB + (4 * g + i) * 200) + (l15 + 15 - 4 * g - i);
        s0[ytB][i] += a2 * bpB[0];
        s1[ytB][i] += a2 * bpB[16];
      }
    }
  }

  // ---- softmax in base-2 (logits pre-scaled); row x per lane; shfl_xor 16,32 reduce ----
  float rl0, rl1;
  {
    float m0 = -1e30f, m1 = -1e30f;
#pragma unroll
    for (int yt = 0; yt < 8; yt++) {
      m0 = fmaxf(fmaxf(m0, s0[yt][0]), s0[yt][1]);
      m0 = fmaxf(fmaxf(m0, s0[yt][2]), s0[yt][3]);
      m1 = fmaxf(fmaxf(m1, s1[yt][0]), s1[yt][1]);
      m1 = fmaxf(fmaxf(m1, s1[yt][2]), s1[yt][3]);
    }
    m0 = fmaxf(m0, __shfl_xor(m0, 16)); m0 = fmaxf(m0, __shfl_xor(m0, 32));
    m1 = fmaxf(m1, __shfl_xor(m1, 16)); m1 = fmaxf(m1, __shfl_xor(m1, 32));
    float l0 = 0.f, l1 = 0.f;
#pragma unroll
    for (int yt = 0; yt < 8; yt++)
#pragma unroll
      for (int i = 0; i < 4; i++) {
        float p0 = exp2f(s0[yt][i] - m0); s0[yt][i] = p0; l0 += p0;
        float p1 = exp2f(s1[yt][i] - m1); s1[yt][i] = p1; l1 += p1;
      }
    l0 += __shfl_xor(l0, 16); l0 += __shfl_xor(l0, 32);
    l1 += __shfl_xor(l1, 16); l1 += __shfl_xor(l1, 32);
    rl0 = 1.f / l0; rl1 = 1.f / l1;
  }

  // ---- Pun stores (cvt_pkrtz): [32 j][140 h] stride 280 ----
#pragma unroll
  for (int yt = 0; yt < 8; yt++) {
    char* pa = sw + l15 * 280 + (16 * yt + 4 * g) * 2;
    *(u32*)pa = pkrtz(s0[yt][0], s0[yt][1]);
    *(u32*)(pa + 4) = pkrtz(s0[yt][2], s0[yt][3]);
    char* pb = sw + (16 + l15) * 280 + (16 * yt + 4 * g) * 2;
    *(u32*)pb = pkrtz(s1[yt][0], s1[yt][1]);
    *(u32*)(pb + 4) = pkrtz(s1[yt][2], s1[yt][3]);
  }
  // ---- PV: A=V (global), B=Pun rows ----
  f32x4 acc0 = zero4, acc1 = zero4;
#pragma unroll
  for (int ky = 0; ky < 4; ky++) {
    h8 vf = *(const h8*)(vb + l15 * 256 + (32 * ky + 8 * g) * 2);
    h8 p0 = *(const h8*)(sw + l15 * 280 + (32 * ky + 8 * g) * 2);
    h8 p1 = *(const h8*)(sw + (16 + l15) * 280 + (32 * ky + 8 * g) * 2);
    acc0 = __builtin_amdgcn_mfma_f32_16x16x32_f16(vf, p0, acc0, 0, 0, 0);
    acc1 = __builtin_amdgcn_mfma_f32_16x16x32_f16(vf, p1, acc1, 0, 0, 0);
  }

  // ---- PVenc: Psk [16 j][172] stride 344, zero once, per-tile store+5 MFMA ----
  for (int i = lane; i < 344; i += 64) *(f32x4*)(sw + i * 16) = zero4;  // 5504B zero
  {  // tile a
#pragma unroll
    for (int yt = 0; yt < 8; yt++)
#pragma unroll
      for (int i = 0; i < 4; i++) {
        int col = 16 * yt + 4 * g + i - l15 + 15;
        *(u16*)(sw + l15 * 344 + col * 2) = f2h_bits(s0[yt][i]);
      }
    int rb_a = 112 - X0a;
#pragma unroll
    for (int t = 0; t < 5; t++) {
      h8 vef = *(const h8*)(veB + l15 * 1024 + (rb_a + 32 * t + 8 * g) * 2);
      h8 skf = *(const h8*)(sw + l15 * 344 + (32 * t + 8 * g) * 2);
      acc0 = __builtin_amdgcn_mfma_f32_16x16x32_f16(vef, skf, acc0, 0, 0, 0);
    }
  }
  {  // tile b (full data-region overwrite; pads stay zero)
#pragma unroll
    for (int yt = 0; yt < 8; yt++)
#pragma unroll
      for (int i = 0; i < 4; i++) {
        int col = 16 * yt + 4 * g + i - l15 + 15;
        *(u16*)(sw + l15 * 344 + col * 2) = f2h_bits(s1[yt][i]);
      }
    int rb_b = 96 - X0a;
#pragma unroll
    for (int t = 0; t < 5; t++) {
      h8 vef = *(const h8*)(veB + l15 * 1024 + (rb_b + 32 * t + 8 * g) * 2);
      h8 skf = *(const h8*)(sw + l15 * 344 + (32 * t + 8 * g) * 2);
      acc1 = __builtin_amdgcn_mfma_f32_16x16x32_f16(vef, skf, acc1, 0, 0, 0);
    }
  }

  // ---- normalize + write otmp[n][c][x] f16 ----
  size_t obase = (size_t)(n * 8 + head) * 2048;
#pragma unroll
  for (int i = 0; i < 4; i++) {
    int d = 4 * g + i;
    otmp[obase + d * 128 + X0a + l15] = (_Float16)(acc0[i] * rl0);
    otmp[obase + d * 128 + X0b + l15] = (_Float16)(acc1[i] * rl1);
  }
}

// ---------------- otmp f16 -> out f32 transpose ----------------
__global__ __launch_bounds__(256) void transpose_h2f(
    const u16* __restrict__ src, float* __restrict__ dst,
    int sb, int sc, int sstr, int db, int dc, int dstr) {
  __shared__ u16 tile[32][33];
  int z = blockIdx.z, b = z >> 7, c = z & 127;
  const u16* s = src + (size_t)b * sb + c * sc;
  float* d = dst + (size_t)b * db + c * dc;
  int tx = threadIdx.x, ty = threadIdx.y;
  int r0 = blockIdx.y * 32, c0 = blockIdx.x * 32;
#pragma unroll
  for (int k = 0; k < 4; k++)
    tile[ty + k * 8][tx] = s[(size_t)(r0 + ty + k * 8) * sstr + c0 + tx];
  __syncthreads();
#pragma unroll
  for (int k = 0; k < 4; k++) {
    u16 hv = tile[tx][ty + k * 8];
    d[(size_t)(c0 + ty + k * 8) * dstr + r0 + tx] = (float)(*(const _Float16*)&hv);
  }
}

extern "C" void kernel_launch(void* const* d_in, const int* in_sizes, int n_in,
                              void* d_out, int out_size, void* d_ws, size_t ws_size,
                              hipStream_t stream) {
  const float* x     = (const float*)d_in[0];
  const float* kqv_w = (const float*)d_in[1];
  const float* kqv_g = (const float*)d_in[2];
  const float* kqv_b = (const float*)d_in[3];
  const float* kqv_m = (const float*)d_in[4];
  const float* kqv_v = (const float*)d_in[5];
  const float* lg    = (const float*)d_in[6];
  const float* lb    = (const float*)d_in[7];
  const float* lm    = (const float*)d_in[8];
  const float* lv    = (const float*)d_in[9];
  const float* rel   = (const float*)d_in[10];
  float* out = (float*)d_out;

  char* ws = (char*)d_ws;
  char* xt2  = ws;                              //  8 MiB f16 swizzled [n][h][c]
  char* qkT  = ws + 8388608;                    // 16 MiB bf16 hi/lo planes
  char* vT   = ws + 25165824;                   //  8 MiB f16 [n,h][d][x]
  _Float16* otmp = (_Float16*)(ws + 33554432);  //  8 MiB f16
  char* whi  = ws + 41943040;                   // 64 KiB
  char* wlo  = ws + 42008576;                   // 64 KiB
  char* relT = ws + 42074112;                   // 32 KiB

  prep_tables<<<33, 256, 0, stream>>>(kqv_w, rel, whi, wlo, relT);
  transpose_x<<<dim3(4, 4, 256), dim3(32, 8), 0, stream>>>(x, xt2);
  kqv_mfma<<<dim3(2, 256), 256, 0, stream>>>(xt2, whi, wlo, kqv_g, kqv_b, kqv_m, kqv_v, qkT, vT);
  attn_mfma8<<<dim3(8, 256), 256, 0, stream>>>(qkT, vT, relT, lg, lb, lm, lv, otmp);
  transpose_h2f<<<dim3(4, 4, 256), dim3(32, 8), 0, stream>>>(
      (const u16*)otmp, out, 2097152, 128, 16384, 2097152, 16384, 128);
}